// Round 11
// baseline (1020.718 us; speedup 1.0000x reference)
//
#include <hip/hip_runtime.h>
#include <hip/hip_bf16.h>
#include <math.h>

#define B_   2
#define S_   4096
#define D_   768
#define H_   12
#define DH_  64
#define BS_  16
#define NB_  256
#define FF_  3072
#define BT_  (B_ * S_)          // 8192 token rows
#define SCALE_F 0.125f          // 1/sqrt(64)

#define NSPLIT 32               // key-dimension splits for edge attention
#define TILES_PER_SPLIT (NB_ / NSPLIT)   // 8
#define NEDGE (B_ * H_ * 2)     // 48 edge (b,h,e) groups

#define DKS 8                   // disc pool k-splits
#define DKC (D_ / DKS)          // 96 rows per split

typedef _Float16 f16x8 __attribute__((ext_vector_type(8)));
typedef _Float16 f16x4 __attribute__((ext_vector_type(4)));
typedef _Float16 f16x2 __attribute__((ext_vector_type(2)));
typedef float    f32x4 __attribute__((ext_vector_type(4)));

#define SV2(v, k) __builtin_shufflevector(v, v, k, (k) + 1)

__device__ __forceinline__ float dot2acc(f16x2 a, f16x2 b, float c)
{
#if __has_builtin(__builtin_amdgcn_fdot2)
    return __builtin_amdgcn_fdot2(a, b, c, false);
#else
    return c + (float)a[0] * (float)b[0] + (float)a[1] * (float)b[1];
#endif
}

// async global->LDS, 16B per lane; LDS dest is wave-uniform base + lane*16
#define GLD16(gp, lp) __builtin_amdgcn_global_load_lds( \
    (const __attribute__((address_space(1))) void*)(gp), \
    (__attribute__((address_space(3))) void*)(lp), 16, 0, 0)

__device__ __forceinline__ float gelu_tanh(float v)
{
    float v3 = v * v * v;
    return 0.5f * v * (1.0f + tanhf(0.79788456080286535588f * (v + 0.044715f * v3)));
}

// ---------------------------------------------------------------------------
// Weight convert + transpose: W fp32 [K][N] -> Wt f16 [N][K]
// ---------------------------------------------------------------------------
__global__ __launch_bounds__(256) void wconvert_kernel(
    const float* __restrict__ W, _Float16* __restrict__ Wt, int K, int N)
{
    __shared__ float tile[32][33];
    int n0 = blockIdx.x * 32, k0 = blockIdx.y * 32;
    int t = threadIdx.x;
    int r = t >> 5, c = t & 31;
#pragma unroll
    for (int rr = 0; rr < 32; rr += 8)
        tile[r + rr][c] = W[(size_t)(k0 + r + rr) * N + n0 + c];
    __syncthreads();
#pragma unroll
    for (int rr = 0; rr < 32; rr += 8)
        Wt[(size_t)(n0 + r + rr) * K + k0 + c] = (_Float16)tile[c][r + rr];
}

// ---------------------------------------------------------------------------
// Embedding gather -> x fp32 and xb f16
// ---------------------------------------------------------------------------
__global__ __launch_bounds__(256) void embed_kernel(
    const int* __restrict__ ids, const float* __restrict__ emb,
    float* __restrict__ x, _Float16* __restrict__ xb)
{
    int row = blockIdx.x;
    int id = ids[row];
    const float* src = emb + (size_t)id * D_;
    float* dst = x + (size_t)row * D_;
    _Float16* dst16 = xb + (size_t)row * D_;
    for (int d = threadIdx.x; d < D_; d += 256) {
        float v = src[d];
        dst[d] = v;
        dst16[d] = (_Float16)v;
    }
}

// ---------------------------------------------------------------------------
// MFMA fp16 GEMM v3b: C[M,N] = A[M,K] @ Wt[N,K]^T + bias
// Wave-tile 128x64 (8 M-frags x 4 N-frags). BK=64.
// Swizzle: 16B-chunk ^= (row&7) involution on stage-source and read.
// r10 FIX: per-kk fragment chunk must be ((kk<<2)|(l>>4)) ^ (l&7) — the
// round-9 `chb + kk*32` was addition where XOR was required (chb can carry
// bit2 from (l&7); chb+4 then overflows into the next row). r8 had it right.
// ---------------------------------------------------------------------------
template<int BM, int ACT, int OUT16>
__global__ __launch_bounds__(BM) void gemm_f16w(
    const _Float16* __restrict__ A, const _Float16* __restrict__ Wt,
    const float* __restrict__ bias, void* __restrict__ Cp,
    int M, int N, int K)
{
    constexpr int NW = BM / 64;          // waves per block: 4 or 2
    constexpr int QA = (BM / 8) / NW;    // A 1KB-chunks per wave = 8
    constexpr int QB = 16 / NW;          // B 1KB-chunks per wave = 4 or 8

    __shared__ __attribute__((aligned(16))) _Float16 As[BM * 64];
    __shared__ __attribute__((aligned(16))) _Float16 Bs[128 * 64];

    int t = threadIdx.x;
    int w = t >> 6, l = t & 63;
    int bm = blockIdx.y * BM, bn = blockIdx.x * 128;
    int wr = (w >> 1) * 128;   // 0 when BM=128
    int wc = (w & 1) * 64;

    f32x4 acc[8][4];
#pragma unroll
    for (int i = 0; i < 8; ++i)
#pragma unroll
        for (int j = 0; j < 4; ++j) acc[i][j] = (f32x4){0.f, 0.f, 0.f, 0.f};

    // staging: chunk m = 8 rows x 64k (1KB). lane l -> row m*8 + (l>>3),
    // LDS 16B-slot (l&7); global source slot (l&7)^((l>>3)&7).
    int rsub = l >> 3;
    int sc = (l & 7) ^ (rsub & 7);
    const _Float16* gA[QA];
    const _Float16* gB[QB];
#pragma unroll
    for (int q = 0; q < QA; ++q) {
        int m = w * QA + q;
        gA[q] = A + (size_t)(bm + m * 8 + rsub) * K + sc * 8;
    }
#pragma unroll
    for (int q = 0; q < QB; ++q) {
        int m = w * QB + q;
        gB[q] = Wt + (size_t)(bn + m * 8 + rsub) * K + sc * 8;
    }

    // fragment LDS offsets per kk-step (ar&7 == l&7 since wr,i*16 are mult of 8)
    int aoff[2][8], boff[2][4];
#pragma unroll
    for (int kk = 0; kk < 2; ++kk) {
        int ch = ((kk << 2) | (l >> 4)) ^ (l & 7);
#pragma unroll
        for (int i = 0; i < 8; ++i)
            aoff[kk][i] = (wr + i * 16 + (l & 15)) * 64 + ch * 8;
#pragma unroll
        for (int j = 0; j < 4; ++j)
            boff[kk][j] = (wc + j * 16 + (l & 15)) * 64 + ch * 8;
    }

    for (int k0 = 0; k0 < K; k0 += 64) {
#pragma unroll
        for (int q = 0; q < QA; ++q)
            GLD16(gA[q] + k0, As + (w * QA + q) * 512);
#pragma unroll
        for (int q = 0; q < QB; ++q)
            GLD16(gB[q] + k0, Bs + (w * QB + q) * 512);
        __syncthreads();   // drains vmcnt (LDS writes)

#pragma unroll
        for (int kk = 0; kk < 2; ++kk) {
            f16x8 bf[4];
#pragma unroll
            for (int j = 0; j < 4; ++j)
                bf[j] = *(const f16x8*)(Bs + boff[kk][j]);
            // half 1: i = 0..3 (af reloaded per half to cap VGPR)
            {
                f16x8 af[4];
#pragma unroll
                for (int i = 0; i < 4; ++i)
                    af[i] = *(const f16x8*)(As + aoff[kk][i]);
#pragma unroll
                for (int i = 0; i < 4; ++i)
#pragma unroll
                    for (int j = 0; j < 4; ++j)
                        acc[i][j] = __builtin_amdgcn_mfma_f32_16x16x32_f16(
                            af[i], bf[j], acc[i][j], 0, 0, 0);
            }
            // half 2: i = 4..7
            {
                f16x8 af[4];
#pragma unroll
                for (int i = 0; i < 4; ++i)
                    af[i] = *(const f16x8*)(As + aoff[kk][i + 4]);
#pragma unroll
                for (int i = 0; i < 4; ++i)
#pragma unroll
                    for (int j = 0; j < 4; ++j)
                        acc[i + 4][j] = __builtin_amdgcn_mfma_f32_16x16x32_f16(
                            af[i], bf[j], acc[i + 4][j], 0, 0, 0);
            }
        }
        __syncthreads();   // protect LDS before next stage
    }

    // epilogue: C/D layout col = lane&15, row = (lane>>4)*4 + reg
#pragma unroll
    for (int i = 0; i < 8; ++i) {
        int rowb = bm + wr + i * 16 + ((l >> 4) << 2);
#pragma unroll
        for (int j = 0; j < 4; ++j) {
            int col = bn + wc + j * 16 + (l & 15);
            float bv = bias[col];
#pragma unroll
            for (int r = 0; r < 4; ++r) {
                float v = acc[i][j][r] + bv;
                if (ACT) v = gelu_tanh(v);
                if (OUT16)
                    ((_Float16*)Cp)[(size_t)(rowb + r) * N + col] = (_Float16)v;
                else
                    ((float*)Cp)[(size_t)(rowb + r) * N + col] = v;
            }
        }
    }
}

// ---------------------------------------------------------------------------
// Attention core (shared body): double-buffered K/V LDS, 1 barrier/tile,
// 2-deep register prefetch, unroll-1 (r7 lesson: compiler unroll -> spills).
// ---------------------------------------------------------------------------
template<int NT, bool EDGE>
__device__ __forceinline__ void attn_block(
    const _Float16* __restrict__ qkv, const int* __restrict__ key_idx,
    _Float16* __restrict__ outp, float* __restrict__ pm,
    float* __restrict__ pl, float* __restrict__ pacc,
    int b, int h, int n, int split, int be,
    _Float16 (*qs)[72], _Float16 (*ks)[16][72], float (*vs)[16][68])
{
    int t = threadIdx.x;
    int l = t & 63;
    int i = t >> 4;        // query row / staging row
    int c = t & 15;
    int c4 = c * 4;

    // stage Q tile; load tile 0 into registers
    *(f16x4*)&qs[i][c4] =
        *(const f16x4*)&qkv[((size_t)(b * S_ + n * BS_ + i)) * (3 * D_) + h * DH_ + c4];
    int kb0 = EDGE ? split * NT : key_idx[n * 7];
    const _Float16* kp0 = qkv + ((size_t)(b * S_ + kb0 * BS_ + i)) * (3 * D_) + D_ + h * DH_;
    f16x4 kr = *(const f16x4*)(kp0 + c4);
    f16x4 vr = *(const f16x4*)(kp0 + D_ + c4);
    __syncthreads();   // qs visible

    // Q row into registers (broadcast reads across lanes sharing i)
    f16x8 qv[8];
#pragma unroll
    for (int d0 = 0; d0 < 8; ++d0) qv[d0] = *(const f16x8*)&qs[i][d0 * 8];

    // write tile 0 into buffer 0; prefetch tile 1
    *(f16x4*)&ks[0][i][c4] = kr;
    {
        f32x4 vf = {(float)vr[0], (float)vr[1], (float)vr[2], (float)vr[3]};
        *(f32x4*)&vs[0][i][c4] = vf;
    }
    if (NT > 1) {
        int kb1 = EDGE ? (split * NT + 1) : key_idx[n * 7 + 1];
        const _Float16* kp1 = qkv + ((size_t)(b * S_ + kb1 * BS_ + i)) * (3 * D_) + D_ + h * DH_;
        kr = *(const f16x4*)(kp1 + c4);
        vr = *(const f16x4*)(kp1 + D_ + c4);
    }
    __syncthreads();   // buffer 0 staged

    float m_old = -1e30f, lsum = 0.f;
    float acc0 = 0.f, acc1 = 0.f, acc2 = 0.f, acc3 = 0.f;
    int base = l & 48;

#pragma unroll 1
    for (int jj = 0; jj < NT; ++jj) {
        int cur = jj & 1;
        if (jj + 1 < NT) {
            *(f16x4*)&ks[cur ^ 1][i][c4] = kr;
            f32x4 vf = {(float)vr[0], (float)vr[1], (float)vr[2], (float)vr[3]};
            *(f32x4*)&vs[cur ^ 1][i][c4] = vf;
        }
        if (jj + 2 < NT) {
            int kb2 = EDGE ? (split * NT + jj + 2) : key_idx[n * 7 + jj + 2];
            const _Float16* kp2 = qkv + ((size_t)(b * S_ + kb2 * BS_ + i)) * (3 * D_) + D_ + h * DH_;
            kr = *(const f16x4*)(kp2 + c4);
            vr = *(const f16x4*)(kp2 + D_ + c4);
        }

        // score: <q_i, k_c> via fdot2 over b128 LDS reads
        float s0 = 0.f, s1 = 0.f;
#pragma unroll
        for (int d0 = 0; d0 < 8; ++d0) {
            f16x8 kv = *(const f16x8*)&ks[cur][c][d0 * 8];
            s0 = dot2acc(SV2(qv[d0], 0), SV2(kv, 0), s0);
            s1 = dot2acc(SV2(qv[d0], 2), SV2(kv, 2), s1);
            s0 = dot2acc(SV2(qv[d0], 4), SV2(kv, 4), s0);
            s1 = dot2acc(SV2(qv[d0], 6), SV2(kv, 6), s1);
        }
        float s = (s0 + s1) * SCALE_F;

        // online softmax within each 16-lane row group
        float rm = s;
#pragma unroll
        for (int off = 8; off; off >>= 1) rm = fmaxf(rm, __shfl_xor(rm, off, 64));
        float m_new = fmaxf(m_old, rm);
        float p = __expf(s - m_new);
        float rs = p;
#pragma unroll
        for (int off = 8; off; off >>= 1) rs += __shfl_xor(rs, off, 64);
        float corr = __expf(m_old - m_new);
        lsum = lsum * corr + rs;
        acc0 *= corr; acc1 *= corr; acc2 *= corr; acc3 *= corr;

        // PV: shuffle-broadcast p, vector V reads
#pragma unroll
        for (int j = 0; j < 16; ++j) {
            float pj = __shfl(p, base + j, 64);
            f32x4 vv = *(const f32x4*)&vs[cur][j][c4];
            acc0 += pj * vv[0];
            acc1 += pj * vv[1];
            acc2 += pj * vv[2];
            acc3 += pj * vv[3];
        }
        m_old = m_new;
        __syncthreads();   // all reads of cur done; writes to cur^1 visible
    }

    if (EDGE) {
        int ps = (be * NSPLIT + split) * 16 + i;
        if (c == 0) { pm[ps] = m_old; pl[ps] = lsum; }
        float* pd = pacc + (size_t)ps * 64 + c4;
        pd[0] = acc0; pd[1] = acc1; pd[2] = acc2; pd[3] = acc3;
    } else {
        float inv = 1.f / lsum;
        _Float16* dst = outp + ((size_t)(b * S_ + n * BS_ + i)) * D_ + h * DH_ + c4;
        dst[0] = (_Float16)(acc0 * inv);
        dst[1] = (_Float16)(acc1 * inv);
        dst[2] = (_Float16)(acc2 * inv);
        dst[3] = (_Float16)(acc3 * inv);
    }
}

// Sparse (non-edge) attention: 2 consecutive n per block
__global__ __launch_bounds__(256) void attn_sparse2(
    const _Float16* __restrict__ qkv, const int* __restrict__ key_idx,
    _Float16* __restrict__ outp)
{
    __shared__ __attribute__((aligned(16))) _Float16 qs[16][72];
    __shared__ __attribute__((aligned(16))) _Float16 ks[2][16][72];
    __shared__ __attribute__((aligned(16))) float    vs[2][16][68];

    int bi = blockIdx.x;
    int p = bi % (NB_ / 2);
    int h = (bi / (NB_ / 2)) % H_;
    int b = bi / ((NB_ / 2) * H_);

#pragma unroll 1
    for (int nn = 0; nn < 2; ++nn) {
        int n = p * 2 + nn;
        if (n == 0 || n == NB_ - 1) continue;   // uniform per-block
        attn_block<7, false>(qkv, key_idx, outp, nullptr, nullptr, nullptr,
                             b, h, n, 0, 0, qs, ks, vs);
        __syncthreads();
    }
}

// Edge attention split-K partials
__global__ __launch_bounds__(256) void attn_edge(
    const _Float16* __restrict__ qkv, float* __restrict__ pm,
    float* __restrict__ pl, float* __restrict__ pacc)
{
    __shared__ __attribute__((aligned(16))) _Float16 qs[16][72];
    __shared__ __attribute__((aligned(16))) _Float16 ks[2][16][72];
    __shared__ __attribute__((aligned(16))) float    vs[2][16][68];

    int bi = blockIdx.x;
    int split = bi % NSPLIT;
    int be = bi / NSPLIT;
    int e = be & 1;
    int h = (be >> 1) % H_;
    int b = be / (2 * H_);
    int n = e ? (NB_ - 1) : 0;

    attn_block<TILES_PER_SPLIT, true>(qkv, nullptr, nullptr, pm, pl, pacc,
                                      b, h, n, split, be, qs, ks, vs);
}

// ---------------------------------------------------------------------------
// Edge attention combine: one block per be group; merge NSPLIT partials.
// ---------------------------------------------------------------------------
__global__ __launch_bounds__(256) void attn_edge_combine(
    const float* __restrict__ pm, const float* __restrict__ pl,
    const float* __restrict__ pacc, _Float16* __restrict__ outp)
{
    int be = blockIdx.x;
    int e = be & 1;
    int h = (be >> 1) % H_;
    int b = be / (2 * H_);
    int n = e ? (NB_ - 1) : 0;

    int t = threadIdx.x;
    int i = t >> 4;
    int c = t & 15;

    float M = -1e30f;
#pragma unroll 4
    for (int s = 0; s < NSPLIT; ++s)
        M = fmaxf(M, pm[(be * NSPLIT + s) * 16 + i]);

    float L = 0.f;
    float acc[4] = {0.f, 0.f, 0.f, 0.f};
    for (int s = 0; s < NSPLIT; ++s) {
        int ps = (be * NSPLIT + s) * 16 + i;
        float wgt = __expf(pm[ps] - M);
        L += pl[ps] * wgt;
#pragma unroll
        for (int u = 0; u < 4; ++u) acc[u] += pacc[(size_t)ps * 64 + c * 4 + u] * wgt;
    }

    float inv = 1.f / L;
    _Float16* dst = outp + ((size_t)(b * S_ + n * BS_ + i)) * D_ + h * DH_ + c * 4;
#pragma unroll
    for (int u = 0; u < 4; ++u) dst[u] = (_Float16)(acc[u] * inv);
}

// ---------------------------------------------------------------------------
// x = LayerNorm(x + g); g is f16; writes fp32 x and f16 xb
// ---------------------------------------------------------------------------
__global__ __launch_bounds__(256) void add_ln_kernel(
    float* __restrict__ x, const _Float16* __restrict__ g,
    const float* __restrict__ gamma, const float* __restrict__ beta,
    _Float16* __restrict__ xb)
{
    int row = blockIdx.x;
    int t = threadIdx.x;
    float* xr = x + (size_t)row * D_;
    const _Float16* gr = g + (size_t)row * D_;
    _Float16* br = xb + (size_t)row * D_;

    float v[3];
    float s = 0.f, s2 = 0.f;
#pragma unroll
    for (int r = 0; r < 3; ++r) {
        int d = t + 256 * r;
        v[r] = xr[d] + (float)gr[d];
        s += v[r];
        s2 += v[r] * v[r];
    }
#pragma unroll
    for (int off = 32; off; off >>= 1) {
        s  += __shfl_xor(s, off, 64);
        s2 += __shfl_xor(s2, off, 64);
    }
    __shared__ float sA[4], sB[4];
    int wave = t >> 6, lane = t & 63;
    if (lane == 0) { sA[wave] = s; sB[wave] = s2; }
    __syncthreads();
    s  = sA[0] + sA[1] + sA[2] + sA[3];
    s2 = sB[0] + sB[1] + sB[2] + sB[3];
    float mean = s * (1.0f / D_);
    float var = s2 * (1.0f / D_) - mean * mean;
    float rstd = rsqrtf(var + 1e-12f);
#pragma unroll
    for (int r = 0; r < 3; ++r) {
        int d = t + 256 * r;
        float o = (v[r] - mean) * rstd * gamma[d] + beta[d];
        xr[d] = o;
        br[d] = (_Float16)o;
    }
}

// ---------------------------------------------------------------------------
__global__ __launch_bounds__(64) void head_logits(
    const float* __restrict__ x, const float* __restrict__ sw,
    const float* __restrict__ ew, float* __restrict__ sl, float* __restrict__ el)
{
    int row = blockIdx.x;
    int lane = threadIdx.x;
    const float* xr = x + (size_t)row * D_;
    float a = 0.f, e = 0.f;
    for (int d = lane; d < D_; d += 64) {
        float xv = xr[d];
        a += xv * sw[d];
        e += xv * ew[d];
    }
#pragma unroll
    for (int off = 32; off; off >>= 1) {
        a += __shfl_xor(a, off, 64);
        e += __shfl_xor(e, off, 64);
    }
    if (lane == 0) { sl[row] = a; el[row] = e; }
}

__global__ __launch_bounds__(256) void softmax_rows(
    const float* __restrict__ sl, const float* __restrict__ el,
    float* __restrict__ outp)
{
    int r = blockIdx.x;
    const float* src = (r < 2 ? sl : el) + (size_t)(r & 1) * S_;
    float* dst = outp + (r < 2 ? 0 : BT_) + (size_t)(r & 1) * S_;
    int t = threadIdx.x;
    int wave = t >> 6, lane = t & 63;
    __shared__ float sm[4], ss[4];

    float m = -1e30f;
    for (int k = t; k < S_; k += 256) m = fmaxf(m, src[k]);
#pragma unroll
    for (int off = 32; off; off >>= 1) m = fmaxf(m, __shfl_xor(m, off, 64));
    if (lane == 0) sm[wave] = m;
    __syncthreads();
    m = fmaxf(fmaxf(sm[0], sm[1]), fmaxf(sm[2], sm[3]));

    float s = 0.f;
    for (int k = t; k < S_; k += 256) s += __expf(src[k] - m);
#pragma unroll
    for (int off = 32; off; off >>= 1) s += __shfl_xor(s, off, 64);
    if (lane == 0) ss[wave] = s;
    __syncthreads();
    s = ss[0] + ss[1] + ss[2] + ss[3];

    float inv = 1.f / s;
    for (int k = t; k < S_; k += 256) dst[k] = __expf(src[k] - m) * inv;
}

// ---------------------------------------------------------------------------
// disc pool GEMV, split across grid; then tiny finish kernel
// ---------------------------------------------------------------------------
__global__ __launch_bounds__(256) void disc_pool_partial(
    const float* __restrict__ x, const float* __restrict__ Wp,
    float* __restrict__ partial)
{
    int jb = blockIdx.x;      // 0..2
    int ks = blockIdx.y;      // 0..DKS-1
    int t = threadIdx.x;
    int j = jb * 256 + t;
    int k0 = ks * DKC;

    __shared__ float xs[DKC];
    if (t < DKC) xs[t] = x[k0 + t];   // x0 = x row 0
    __syncthreads();

    float s = 0.f;
#pragma unroll 8
    for (int kk = 0; kk < DKC; ++kk)
        s += xs[kk] * Wp[(size_t)(k0 + kk) * D_ + j];
    partial[ks * D_ + j] = s;
}

__global__ __launch_bounds__(256) void disc_finish(
    const float* __restrict__ partial, const float* __restrict__ bp,
    const float* __restrict__ d1W, const float* __restrict__ d1b,
    const float* __restrict__ d2W, const float* __restrict__ d2b,
    float* __restrict__ out2)
{
    __shared__ float pool[D_];
    __shared__ float h1[20];
    int t = threadIdx.x;
    for (int j = t; j < D_; j += 256) {
        float s = bp[j];
#pragma unroll
        for (int ks = 0; ks < DKS; ++ks) s += partial[ks * D_ + j];
        pool[j] = tanhf(s);
    }
    __syncthreads();
    if (t < 20) {
        float s = d1b[t];
        for (int k = 0; k < D_; ++k) s += pool[k] * d1W[k * 20 + t];
        h1[t] = s;
    }
    __syncthreads();
    if (t == 0) {
        float d0 = d2b[0], d1v = d2b[1];
#pragma unroll
        for (int u = 0; u < 20; ++u) {
            d0  += h1[u] * d2W[u * 2 + 0];
            d1v += h1[u] * d2W[u * 2 + 1];
        }
        float m = fmaxf(d0, d1v);
        float e0 = __expf(d0 - m), e1 = __expf(d1v - m);
        float inv = 1.f / (e0 + e1);
        out2[0] = e0 * inv;
        out2[1] = e1 * inv;
    }
}

// ---------------------------------------------------------------------------
extern "C" void kernel_launch(void* const* d_in, const int* in_sizes, int n_in,
                              void* d_out, int out_size, void* d_ws, size_t ws_size,
                              hipStream_t stream)
{
    const int*   ids   = (const int*)d_in[0];
    const int*   kbi   = (const int*)d_in[1];
    const float* emb   = (const float*)d_in[2];
    const float* Wqkv  = (const float*)d_in[3];
    const float* bqkv  = (const float*)d_in[4];
    const float* Wo    = (const float*)d_in[5];
    const float* bo    = (const float*)d_in[6];
    const float* ln1g  = (const float*)d_in[7];
    const float* ln1b  = (const float*)d_in[8];
    const float* Wff1  = (const float*)d_in[9];
    const float* bff1  = (const float*)d_in[10];
    const float* Wff2  = (const float*)d_in[11];
    const float* bff2  = (const float*)d_in[12];
    const float* ln2g  = (const float*)d_in[13];
    const float* ln2b  = (const float*)d_in[14];
    const float* Wp    = (const float*)d_in[15];
    const float* bp    = (const float*)d_in[16];
    const float* sw    = (const float*)d_in[17];
    const float* ew    = (const float*)d_in[18];
    const float* d1W   = (const float*)d_in[19];
    const float* d1b   = (const float*)d_in[20];
    const float* d2W   = (const float*)d_in[21];
    const float* d2b   = (const float*)d_in[22];
    float* outp = (float*)d_out;

    // workspace carve (float units)
    float* ws   = (float*)d_ws;
    float* x    = ws;                          // BT_*D_ f32
    float* xbf  = x   + (size_t)BT_ * D_;      // f16 xb
    float* r1f  = xbf + (size_t)BT_ * D_ / 2;  // f16 qkv / f16 h
    float* abf  = r1f + (size_t)BT_ * FF_ / 2; // f16 attn out
    float* r2   = abf + (size_t)BT_ * D_ / 2;  // partials (early) / f16 g (late)
    float* wtf  = r2  + (size_t)BT_ * D_;      // f16 weights
    float* sl   = wtf + 7077888;
    float* el   = sl  + BT_;
    float* dpar = el  + BT_;                   // DKS * D_ disc partials

    _Float16* xb    = (_Float16*)xbf;
    _Float16* qkv16 = (_Float16*)r1f;
    _Float16* h16   = (_Float16*)r1f;
    _Float16* ab    = (_Float16*)abf;
    float* pm   = r2;
    float* pl   = r2 + NEDGE * NSPLIT * 16;
    float* pacc = pl + NEDGE * NSPLIT * 16;
    _Float16* g16 = (_Float16*)r2;   // aliased; partials dead once proj runs

    _Float16* Wt    = (_Float16*)wtf;
    _Float16* WqkvT = Wt;
    _Float16* WoT   = WqkvT + (size_t)2 * 2304 * 768;
    _Float16* Wff1T = WoT   + (size_t)2 * 768 * 768;
    _Float16* Wff2T = Wff1T + (size_t)2 * 3072 * 768;

    for (int l = 0; l < 2; ++l) {
        wconvert_kernel<<<dim3(2304/32, 768/32), 256, 0, stream>>>(
            Wqkv + (size_t)l * 768 * 2304, WqkvT + (size_t)l * 2304 * 768, 768, 2304);
        wconvert_kernel<<<dim3(768/32, 768/32), 256, 0, stream>>>(
            Wo + (size_t)l * 768 * 768, WoT + (size_t)l * 768 * 768, 768, 768);
        wconvert_kernel<<<dim3(3072/32, 768/32), 256, 0, stream>>>(
            Wff1 + (size_t)l * 768 * 3072, Wff1T + (size_t)l * 3072 * 768, 768, 3072);
        wconvert_kernel<<<dim3(768/32, 3072/32), 256, 0, stream>>>(
            Wff2 + (size_t)l * 3072 * 768, Wff2T + (size_t)l * 768 * 3072, 3072, 768);
    }

    embed_kernel<<<BT_, 256, 0, stream>>>(ids, emb, x, xb);

    for (int l = 0; l < 2; ++l) {
        // qkv: [8192 x 2304], K=768 — 256x128 blocks, grid 18x32
        gemm_f16w<256,0,1><<<dim3(2304/128, BT_/256), 256, 0, stream>>>(
            xb, WqkvT + (size_t)l * 2304 * 768, bqkv + (size_t)l * 3 * D_,
            qkv16, BT_, 3 * D_, D_);
        attn_sparse2<<<B_ * H_ * (NB_ / 2), 256, 0, stream>>>(qkv16, kbi, ab);
        attn_edge<<<NEDGE * NSPLIT, 256, 0, stream>>>(qkv16, pm, pl, pacc);
        attn_edge_combine<<<NEDGE, 256, 0, stream>>>(pm, pl, pacc, ab);
        // proj: [8192 x 768], K=768 — 128x128 blocks, grid 6x64
        gemm_f16w<128,0,1><<<dim3(768/128, BT_/128), 128, 0, stream>>>(
            ab, WoT + (size_t)l * 768 * 768, bo + (size_t)l * D_,
            g16, BT_, D_, D_);
        add_ln_kernel<<<BT_, 256, 0, stream>>>(x, g16, ln1g + (size_t)l * D_, ln1b + (size_t)l * D_, xb);
        // ff1 + gelu: [8192 x 3072], K=768 — 256x128 blocks, grid 24x32
        gemm_f16w<256,1,1><<<dim3(3072/128, BT_/256), 256, 0, stream>>>(
            xb, Wff1T + (size_t)l * 3072 * 768, bff1 + (size_t)l * FF_,
            h16, BT_, FF_, D_);
        // ff2: [8192 x 768], K=3072 — 128x128 blocks, grid 6x64
        gemm_f16w<128,0,1><<<dim3(768/128, BT_/128), 128, 0, stream>>>(
            h16, Wff2T + (size_t)l * 768 * 3072, bff2 + (size_t)l * D_,
            g16, BT_, D_, FF_);
        add_ln_kernel<<<BT_, 256, 0, stream>>>(x, g16, ln2g + (size_t)l * D_, ln2b + (size_t)l * D_, xb);
    }

    head_logits<<<BT_, 64, 0, stream>>>(x, sw, ew, sl, el);
    softmax_rows<<<4, 256, 0, stream>>>(sl, el, outp);
    disc_pool_partial<<<dim3(3, DKS), 256, 0, stream>>>(x, Wp, dpar);
    disc_finish<<<1, 256, 0, stream>>>(dpar, bp, d1W, d1b, d2W, d2b, outp + 2 * BT_);
}

// Round 12
// 752.589 us; speedup vs baseline: 1.3563x; 1.3563x over previous
//
#include <hip/hip_runtime.h>
#include <hip/hip_bf16.h>
#include <math.h>

#define B_   2
#define S_   4096
#define D_   768
#define H_   12
#define DH_  64
#define BS_  16
#define NB_  256
#define FF_  3072
#define BT_  (B_ * S_)          // 8192 token rows
#define SCALE_F 0.125f          // 1/sqrt(64)

#define NSPLIT 32               // key-dimension splits for edge attention
#define TILES_PER_SPLIT (NB_ / NSPLIT)   // 8
#define NEDGE (B_ * H_ * 2)     // 48 edge (b,h,e) groups

#define DKS 8                   // disc pool k-splits
#define DKC (D_ / DKS)          // 96 rows per split

typedef _Float16 f16x8 __attribute__((ext_vector_type(8)));
typedef _Float16 f16x4 __attribute__((ext_vector_type(4)));
typedef _Float16 f16x2 __attribute__((ext_vector_type(2)));
typedef float    f32x4 __attribute__((ext_vector_type(4)));

#define SV2(v, k) __builtin_shufflevector(v, v, k, (k) + 1)

__device__ __forceinline__ float dot2acc(f16x2 a, f16x2 b, float c)
{
#if __has_builtin(__builtin_amdgcn_fdot2)
    return __builtin_amdgcn_fdot2(a, b, c, false);
#else
    return c + (float)a[0] * (float)b[0] + (float)a[1] * (float)b[1];
#endif
}

// async global->LDS, 16B per lane; LDS dest is wave-uniform base + lane*16
#define GLD16(gp, lp) __builtin_amdgcn_global_load_lds( \
    (const __attribute__((address_space(1))) void*)(gp), \
    (__attribute__((address_space(3))) void*)(lp), 16, 0, 0)

__device__ __forceinline__ float gelu_tanh(float v)
{
    float v3 = v * v * v;
    return 0.5f * v * (1.0f + tanhf(0.79788456080286535588f * (v + 0.044715f * v3)));
}

// ---------------------------------------------------------------------------
// Weight convert + transpose: W fp32 [K][N] -> Wt f16 [N][K]
// ---------------------------------------------------------------------------
__global__ __launch_bounds__(256) void wconvert_kernel(
    const float* __restrict__ W, _Float16* __restrict__ Wt, int K, int N)
{
    __shared__ float tile[32][33];
    int n0 = blockIdx.x * 32, k0 = blockIdx.y * 32;
    int t = threadIdx.x;
    int r = t >> 5, c = t & 31;
#pragma unroll
    for (int rr = 0; rr < 32; rr += 8)
        tile[r + rr][c] = W[(size_t)(k0 + r + rr) * N + n0 + c];
    __syncthreads();
#pragma unroll
    for (int rr = 0; rr < 32; rr += 8)
        Wt[(size_t)(n0 + r + rr) * K + k0 + c] = (_Float16)tile[c][r + rr];
}

// ---------------------------------------------------------------------------
// Embedding gather -> x fp32 and xb f16
// ---------------------------------------------------------------------------
__global__ __launch_bounds__(256) void embed_kernel(
    const int* __restrict__ ids, const float* __restrict__ emb,
    float* __restrict__ x, _Float16* __restrict__ xb)
{
    int row = blockIdx.x;
    int id = ids[row];
    const float* src = emb + (size_t)id * D_;
    float* dst = x + (size_t)row * D_;
    _Float16* dst16 = xb + (size_t)row * D_;
    for (int d = threadIdx.x; d < D_; d += 256) {
        float v = src[d];
        dst[d] = v;
        dst16[d] = (_Float16)v;
    }
}

// ---------------------------------------------------------------------------
// MFMA fp16 GEMM (round-8 verified kernel): C = A[M,K] @ Wt[N,K]^T + bias
// 128x128 tile, BK=64 (32 MFMA between barriers), 4 waves, 4x4 frags/wave.
// Swizzle: 16B-chunk ^= (row&7) involution on stage-source and read.
// (r11 lesson: the 128x64 wave-tile variant halved occupancy and lost
// cross-block latency overlap — reverted to this known-824µs version.)
// ---------------------------------------------------------------------------
template<int ACT, int OUT16>
__global__ __launch_bounds__(256) void gemm_f16(
    const _Float16* __restrict__ A, const _Float16* __restrict__ Wt,
    const float* __restrict__ bias, void* __restrict__ Cp,
    int M, int N, int K)
{
    __shared__ __attribute__((aligned(16))) _Float16 As[128 * 64];
    __shared__ __attribute__((aligned(16))) _Float16 Bs[128 * 64];

    int t = threadIdx.x;
    int w = t >> 6, l = t & 63;
    int bm = blockIdx.y * 128, bn = blockIdx.x * 128;
    int wr = (w >> 1) * 64, wc = (w & 1) * 64;

    f32x4 acc[4][4];
#pragma unroll
    for (int i = 0; i < 4; ++i)
#pragma unroll
        for (int j = 0; j < 4; ++j) acc[i][j] = (f32x4){0.f, 0.f, 0.f, 0.f};

    // staging: wave w owns 1KB chunks {4w..4w+3} of each 16KB tile.
    // chunk m covers rows [m*8, m*8+8); lane l -> row m*8 + (l>>3),
    // in-row 16B-chunk (l&7) at LDS; global source chunk (l&7)^(row&7).
    const _Float16* gA[4];
    const _Float16* gB[4];
#pragma unroll
    for (int q = 0; q < 4; ++q) {
        int m = w * 4 + q;
        int row = m * 8 + (l >> 3);
        int sc = (l & 7) ^ (row & 7);
        gA[q] = A  + (size_t)(bm + row) * K + sc * 8;
        gB[q] = Wt + (size_t)(bn + row) * K + sc * 8;
    }

    // fragment LDS offsets (ar&7 == l&7 since wr,i*16 are multiples of 8)
    int aoff[2][4], boff[2][4];
#pragma unroll
    for (int kk = 0; kk < 2; ++kk)
#pragma unroll
        for (int i = 0; i < 4; ++i) {
            int ar = wr + i * 16 + (l & 15);
            int ch = (kk * 4 + (l >> 4)) ^ (l & 7);
            aoff[kk][i] = ar * 64 + ch * 8;
            int br = wc + i * 16 + (l & 15);
            boff[kk][i] = br * 64 + ch * 8;
        }

    for (int k0 = 0; k0 < K; k0 += 64) {
#pragma unroll
        for (int q = 0; q < 4; ++q) {
            int m = w * 4 + q;
            GLD16(gA[q] + k0, As + m * 512);
            GLD16(gB[q] + k0, Bs + m * 512);
        }
        __syncthreads();   // drains vmcnt (LDS writes) + lgkm

        f16x8 af[2][4], bf[2][4];
#pragma unroll
        for (int kk = 0; kk < 2; ++kk)
#pragma unroll
            for (int i = 0; i < 4; ++i) {
                af[kk][i] = *(const f16x8*)(As + aoff[kk][i]);
                bf[kk][i] = *(const f16x8*)(Bs + boff[kk][i]);
            }
#pragma unroll
        for (int kk = 0; kk < 2; ++kk)
#pragma unroll
            for (int i = 0; i < 4; ++i)
#pragma unroll
                for (int j = 0; j < 4; ++j)
                    acc[i][j] = __builtin_amdgcn_mfma_f32_16x16x32_f16(
                        af[kk][i], bf[kk][j], acc[i][j], 0, 0, 0);
        __syncthreads();   // protect LDS before next stage
    }

    // epilogue: C/D layout col = lane&15, row = (lane>>4)*4 + reg
#pragma unroll
    for (int i = 0; i < 4; ++i) {
        int rowb = bm + wr + i * 16 + ((l >> 4) << 2);
#pragma unroll
        for (int j = 0; j < 4; ++j) {
            int col = bn + wc + j * 16 + (l & 15);
            float bv = bias[col];
#pragma unroll
            for (int r = 0; r < 4; ++r) {
                float v = acc[i][j][r] + bv;
                if (ACT) v = gelu_tanh(v);
                if (OUT16)
                    ((_Float16*)Cp)[(size_t)(rowb + r) * N + col] = (_Float16)v;
                else
                    ((float*)Cp)[(size_t)(rowb + r) * N + col] = v;
            }
        }
    }
}

// ---------------------------------------------------------------------------
// Attention core: double-buffered K/V LDS (1 barrier/tile), 2-deep register
// prefetch, unroll-1 (r7 lesson). r11 change: PV broadcast via LDS instead
// of 16 ds_bpermute — thread (i,c) writes ps[i][c]; the 16 lanes of a row
// group are in ONE wave (i = 4w..4w+3 for wave w), so the read-back of
// ps[i][0..15] as 4x b128 needs no barrier (intra-wave lockstep + compiler
// lgkmcnt). 16 bpermute -> 1 ds_write + 4 ds_read_b128 per tile.
// ---------------------------------------------------------------------------
template<int NT, bool EDGE>
__device__ __forceinline__ void attn_block(
    const _Float16* __restrict__ qkv, const int* __restrict__ key_idx,
    _Float16* __restrict__ outp, float* __restrict__ pm,
    float* __restrict__ pl, float* __restrict__ pacc,
    int b, int h, int n, int split, int be,
    _Float16 (*qs)[72], _Float16 (*ks)[16][72], float (*vs)[16][68],
    float (*ps)[20])
{
    int t = threadIdx.x;
    int i = t >> 4;        // query row / staging row
    int c = t & 15;
    int c4 = c * 4;

    // stage Q tile; load tile 0 into registers
    *(f16x4*)&qs[i][c4] =
        *(const f16x4*)&qkv[((size_t)(b * S_ + n * BS_ + i)) * (3 * D_) + h * DH_ + c4];
    int kb0 = EDGE ? split * NT : key_idx[n * 7];
    const _Float16* kp0 = qkv + ((size_t)(b * S_ + kb0 * BS_ + i)) * (3 * D_) + D_ + h * DH_;
    f16x4 kr = *(const f16x4*)(kp0 + c4);
    f16x4 vr = *(const f16x4*)(kp0 + D_ + c4);
    __syncthreads();   // qs visible

    // Q row into registers (broadcast reads across lanes sharing i)
    f16x8 qv[8];
#pragma unroll
    for (int d0 = 0; d0 < 8; ++d0) qv[d0] = *(const f16x8*)&qs[i][d0 * 8];

    // write tile 0 into buffer 0; prefetch tile 1
    *(f16x4*)&ks[0][i][c4] = kr;
    {
        f32x4 vf = {(float)vr[0], (float)vr[1], (float)vr[2], (float)vr[3]};
        *(f32x4*)&vs[0][i][c4] = vf;
    }
    if (NT > 1) {
        int kb1 = EDGE ? (split * NT + 1) : key_idx[n * 7 + 1];
        const _Float16* kp1 = qkv + ((size_t)(b * S_ + kb1 * BS_ + i)) * (3 * D_) + D_ + h * DH_;
        kr = *(const f16x4*)(kp1 + c4);
        vr = *(const f16x4*)(kp1 + D_ + c4);
    }
    __syncthreads();   // buffer 0 staged

    float m_old = -1e30f, lsum = 0.f;
    float acc0 = 0.f, acc1 = 0.f, acc2 = 0.f, acc3 = 0.f;

#pragma unroll 1
    for (int jj = 0; jj < NT; ++jj) {
        int cur = jj & 1;
        if (jj + 1 < NT) {
            *(f16x4*)&ks[cur ^ 1][i][c4] = kr;
            f32x4 vf = {(float)vr[0], (float)vr[1], (float)vr[2], (float)vr[3]};
            *(f32x4*)&vs[cur ^ 1][i][c4] = vf;
        }
        if (jj + 2 < NT) {
            int kb2 = EDGE ? (split * NT + jj + 2) : key_idx[n * 7 + jj + 2];
            const _Float16* kp2 = qkv + ((size_t)(b * S_ + kb2 * BS_ + i)) * (3 * D_) + D_ + h * DH_;
            kr = *(const f16x4*)(kp2 + c4);
            vr = *(const f16x4*)(kp2 + D_ + c4);
        }

        // score: <q_i, k_c> via fdot2 over b128 LDS reads
        float s0 = 0.f, s1 = 0.f;
#pragma unroll
        for (int d0 = 0; d0 < 8; ++d0) {
            f16x8 kv = *(const f16x8*)&ks[cur][c][d0 * 8];
            s0 = dot2acc(SV2(qv[d0], 0), SV2(kv, 0), s0);
            s1 = dot2acc(SV2(qv[d0], 2), SV2(kv, 2), s1);
            s0 = dot2acc(SV2(qv[d0], 4), SV2(kv, 4), s0);
            s1 = dot2acc(SV2(qv[d0], 6), SV2(kv, 6), s1);
        }
        float s = (s0 + s1) * SCALE_F;

        // online softmax within each 16-lane row group
        float rm = s;
#pragma unroll
        for (int off = 8; off; off >>= 1) rm = fmaxf(rm, __shfl_xor(rm, off, 64));
        float m_new = fmaxf(m_old, rm);
        float p = __expf(s - m_new);
        float rs = p;
#pragma unroll
        for (int off = 8; off; off >>= 1) rs += __shfl_xor(rs, off, 64);
        float corr = __expf(m_old - m_new);
        lsum = lsum * corr + rs;
        acc0 *= corr; acc1 *= corr; acc2 *= corr; acc3 *= corr;

        // PV: p shared via LDS within the row group (intra-wave, no barrier)
        ps[i][c] = p;
        float parr[16];
        *(f32x4*)&parr[0]  = *(const f32x4*)&ps[i][0];
        *(f32x4*)&parr[4]  = *(const f32x4*)&ps[i][4];
        *(f32x4*)&parr[8]  = *(const f32x4*)&ps[i][8];
        *(f32x4*)&parr[12] = *(const f32x4*)&ps[i][12];
#pragma unroll
        for (int j = 0; j < 16; ++j) {
            f32x4 vv = *(const f32x4*)&vs[cur][j][c4];
            acc0 += parr[j] * vv[0];
            acc1 += parr[j] * vv[1];
            acc2 += parr[j] * vv[2];
            acc3 += parr[j] * vv[3];
        }
        m_old = m_new;
        __syncthreads();   // all reads of cur done; writes to cur^1 visible
    }

    if (EDGE) {
        int psx = (be * NSPLIT + split) * 16 + i;
        if (c == 0) { pm[psx] = m_old; pl[psx] = lsum; }
        float* pd = pacc + (size_t)psx * 64 + c4;
        pd[0] = acc0; pd[1] = acc1; pd[2] = acc2; pd[3] = acc3;
    } else {
        float inv = 1.f / lsum;
        _Float16* dst = outp + ((size_t)(b * S_ + n * BS_ + i)) * D_ + h * DH_ + c4;
        dst[0] = (_Float16)(acc0 * inv);
        dst[1] = (_Float16)(acc1 * inv);
        dst[2] = (_Float16)(acc2 * inv);
        dst[3] = (_Float16)(acc3 * inv);
    }
}

// Sparse (non-edge) attention: one (b,h,n) per block (r9 pairing was neutral)
__global__ __launch_bounds__(256) void attn_sparse(
    const _Float16* __restrict__ qkv, const int* __restrict__ key_idx,
    _Float16* __restrict__ outp)
{
    __shared__ __attribute__((aligned(16))) _Float16 qs[16][72];
    __shared__ __attribute__((aligned(16))) _Float16 ks[2][16][72];
    __shared__ __attribute__((aligned(16))) float    vs[2][16][68];
    __shared__ __attribute__((aligned(16))) float    ps[16][20];

    int bi = blockIdx.x;
    int n = bi % NB_;
    if (n == 0 || n == NB_ - 1) return;
    int h = (bi / NB_) % H_;
    int b = bi / (NB_ * H_);

    attn_block<7, false>(qkv, key_idx, outp, nullptr, nullptr, nullptr,
                         b, h, n, 0, 0, qs, ks, vs, ps);
}

// Edge attention split-K partials
__global__ __launch_bounds__(256) void attn_edge(
    const _Float16* __restrict__ qkv, float* __restrict__ pm,
    float* __restrict__ pl, float* __restrict__ pacc)
{
    __shared__ __attribute__((aligned(16))) _Float16 qs[16][72];
    __shared__ __attribute__((aligned(16))) _Float16 ks[2][16][72];
    __shared__ __attribute__((aligned(16))) float    vs[2][16][68];
    __shared__ __attribute__((aligned(16))) float    ps[16][20];

    int bi = blockIdx.x;
    int split = bi % NSPLIT;
    int be = bi / NSPLIT;
    int e = be & 1;
    int h = (be >> 1) % H_;
    int b = be / (2 * H_);
    int n = e ? (NB_ - 1) : 0;

    attn_block<TILES_PER_SPLIT, true>(qkv, nullptr, nullptr, pm, pl, pacc,
                                      b, h, n, split, be, qs, ks, vs, ps);
}

// ---------------------------------------------------------------------------
// Edge attention combine: one block per be group; merge NSPLIT partials.
// ---------------------------------------------------------------------------
__global__ __launch_bounds__(256) void attn_edge_combine(
    const float* __restrict__ pm, const float* __restrict__ pl,
    const float* __restrict__ pacc, _Float16* __restrict__ outp)
{
    int be = blockIdx.x;
    int e = be & 1;
    int h = (be >> 1) % H_;
    int b = be / (2 * H_);
    int n = e ? (NB_ - 1) : 0;

    int t = threadIdx.x;
    int i = t >> 4;
    int c = t & 15;

    float M = -1e30f;
#pragma unroll 4
    for (int s = 0; s < NSPLIT; ++s)
        M = fmaxf(M, pm[(be * NSPLIT + s) * 16 + i]);

    float L = 0.f;
    float acc[4] = {0.f, 0.f, 0.f, 0.f};
    for (int s = 0; s < NSPLIT; ++s) {
        int ps = (be * NSPLIT + s) * 16 + i;
        float wgt = __expf(pm[ps] - M);
        L += pl[ps] * wgt;
#pragma unroll
        for (int u = 0; u < 4; ++u) acc[u] += pacc[(size_t)ps * 64 + c * 4 + u] * wgt;
    }

    float inv = 1.f / L;
    _Float16* dst = outp + ((size_t)(b * S_ + n * BS_ + i)) * D_ + h * DH_ + c * 4;
#pragma unroll
    for (int u = 0; u < 4; ++u) dst[u] = (_Float16)(acc[u] * inv);
}

// ---------------------------------------------------------------------------
// x = LayerNorm(x + g); g is f16; writes fp32 x and f16 xb
// ---------------------------------------------------------------------------
__global__ __launch_bounds__(256) void add_ln_kernel(
    float* __restrict__ x, const _Float16* __restrict__ g,
    const float* __restrict__ gamma, const float* __restrict__ beta,
    _Float16* __restrict__ xb)
{
    int row = blockIdx.x;
    int t = threadIdx.x;
    float* xr = x + (size_t)row * D_;
    const _Float16* gr = g + (size_t)row * D_;
    _Float16* br = xb + (size_t)row * D_;

    float v[3];
    float s = 0.f, s2 = 0.f;
#pragma unroll
    for (int r = 0; r < 3; ++r) {
        int d = t + 256 * r;
        v[r] = xr[d] + (float)gr[d];
        s += v[r];
        s2 += v[r] * v[r];
    }
#pragma unroll
    for (int off = 32; off; off >>= 1) {
        s  += __shfl_xor(s, off, 64);
        s2 += __shfl_xor(s2, off, 64);
    }
    __shared__ float sA[4], sB[4];
    int wave = t >> 6, lane = t & 63;
    if (lane == 0) { sA[wave] = s; sB[wave] = s2; }
    __syncthreads();
    s  = sA[0] + sA[1] + sA[2] + sA[3];
    s2 = sB[0] + sB[1] + sB[2] + sB[3];
    float mean = s * (1.0f / D_);
    float var = s2 * (1.0f / D_) - mean * mean;
    float rstd = rsqrtf(var + 1e-12f);
#pragma unroll
    for (int r = 0; r < 3; ++r) {
        int d = t + 256 * r;
        float o = (v[r] - mean) * rstd * gamma[d] + beta[d];
        xr[d] = o;
        br[d] = (_Float16)o;
    }
}

// ---------------------------------------------------------------------------
__global__ __launch_bounds__(64) void head_logits(
    const float* __restrict__ x, const float* __restrict__ sw,
    const float* __restrict__ ew, float* __restrict__ sl, float* __restrict__ el)
{
    int row = blockIdx.x;
    int lane = threadIdx.x;
    const float* xr = x + (size_t)row * D_;
    float a = 0.f, e = 0.f;
    for (int d = lane; d < D_; d += 64) {
        float xv = xr[d];
        a += xv * sw[d];
        e += xv * ew[d];
    }
#pragma unroll
    for (int off = 32; off; off >>= 1) {
        a += __shfl_xor(a, off, 64);
        e += __shfl_xor(e, off, 64);
    }
    if (lane == 0) { sl[row] = a; el[row] = e; }
}

__global__ __launch_bounds__(256) void softmax_rows(
    const float* __restrict__ sl, const float* __restrict__ el,
    float* __restrict__ outp)
{
    int r = blockIdx.x;
    const float* src = (r < 2 ? sl : el) + (size_t)(r & 1) * S_;
    float* dst = outp + (r < 2 ? 0 : BT_) + (size_t)(r & 1) * S_;
    int t = threadIdx.x;
    int wave = t >> 6, lane = t & 63;
    __shared__ float sm[4], ss[4];

    float m = -1e30f;
    for (int k = t; k < S_; k += 256) m = fmaxf(m, src[k]);
#pragma unroll
    for (int off = 32; off; off >>= 1) m = fmaxf(m, __shfl_xor(m, off, 64));
    if (lane == 0) sm[wave] = m;
    __syncthreads();
    m = fmaxf(fmaxf(sm[0], sm[1]), fmaxf(sm[2], sm[3]));

    float s = 0.f;
    for (int k = t; k < S_; k += 256) s += __expf(src[k] - m);
#pragma unroll
    for (int off = 32; off; off >>= 1) s += __shfl_xor(s, off, 64);
    if (lane == 0) ss[wave] = s;
    __syncthreads();
    s = ss[0] + ss[1] + ss[2] + ss[3];

    float inv = 1.f / s;
    for (int k = t; k < S_; k += 256) dst[k] = __expf(src[k] - m) * inv;
}

// ---------------------------------------------------------------------------
// disc pool GEMV, split across grid; then tiny finish kernel
// ---------------------------------------------------------------------------
__global__ __launch_bounds__(256) void disc_pool_partial(
    const float* __restrict__ x, const float* __restrict__ Wp,
    float* __restrict__ partial)
{
    int jb = blockIdx.x;      // 0..2
    int ks = blockIdx.y;      // 0..DKS-1
    int t = threadIdx.x;
    int j = jb * 256 + t;
    int k0 = ks * DKC;

    __shared__ float xs[DKC];
    if (t < DKC) xs[t] = x[k0 + t];   // x0 = x row 0
    __syncthreads();

    float s = 0.f;
#pragma unroll 8
    for (int kk = 0; kk < DKC; ++kk)
        s += xs[kk] * Wp[(size_t)(k0 + kk) * D_ + j];
    partial[ks * D_ + j] = s;
}

__global__ __launch_bounds__(256) void disc_finish(
    const float* __restrict__ partial, const float* __restrict__ bp,
    const float* __restrict__ d1W, const float* __restrict__ d1b,
    const float* __restrict__ d2W, const float* __restrict__ d2b,
    float* __restrict__ out2)
{
    __shared__ float pool[D_];
    __shared__ float h1[20];
    int t = threadIdx.x;
    for (int j = t; j < D_; j += 256) {
        float s = bp[j];
#pragma unroll
        for (int ks = 0; ks < DKS; ++ks) s += partial[ks * D_ + j];
        pool[j] = tanhf(s);
    }
    __syncthreads();
    if (t < 20) {
        float s = d1b[t];
        for (int k = 0; k < D_; ++k) s += pool[k] * d1W[k * 20 + t];
        h1[t] = s;
    }
    __syncthreads();
    if (t == 0) {
        float d0 = d2b[0], d1v = d2b[1];
#pragma unroll
        for (int u = 0; u < 20; ++u) {
            d0  += h1[u] * d2W[u * 2 + 0];
            d1v += h1[u] * d2W[u * 2 + 1];
        }
        float m = fmaxf(d0, d1v);
        float e0 = __expf(d0 - m), e1 = __expf(d1v - m);
        float inv = 1.f / (e0 + e1);
        out2[0] = e0 * inv;
        out2[1] = e1 * inv;
    }
}

// ---------------------------------------------------------------------------
extern "C" void kernel_launch(void* const* d_in, const int* in_sizes, int n_in,
                              void* d_out, int out_size, void* d_ws, size_t ws_size,
                              hipStream_t stream)
{
    const int*   ids   = (const int*)d_in[0];
    const int*   kbi   = (const int*)d_in[1];
    const float* emb   = (const float*)d_in[2];
    const float* Wqkv  = (const float*)d_in[3];
    const float* bqkv  = (const float*)d_in[4];
    const float* Wo    = (const float*)d_in[5];
    const float* bo    = (const float*)d_in[6];
    const float* ln1g  = (const float*)d_in[7];
    const float* ln1b  = (const float*)d_in[8];
    const float* Wff1  = (const float*)d_in[9];
    const float* bff1  = (const float*)d_in[10];
    const float* Wff2  = (const float*)d_in[11];
    const float* bff2  = (const float*)d_in[12];
    const float* ln2g  = (const float*)d_in[13];
    const float* ln2b  = (const float*)d_in[14];
    const float* Wp    = (const float*)d_in[15];
    const float* bp    = (const float*)d_in[16];
    const float* sw    = (const float*)d_in[17];
    const float* ew    = (const float*)d_in[18];
    const float* d1W   = (const float*)d_in[19];
    const float* d1b   = (const float*)d_in[20];
    const float* d2W   = (const float*)d_in[21];
    const float* d2b   = (const float*)d_in[22];
    float* outp = (float*)d_out;

    // workspace carve (float units)
    float* ws   = (float*)d_ws;
    float* x    = ws;                          // BT_*D_ f32
    float* xbf  = x   + (size_t)BT_ * D_;      // f16 xb
    float* r1f  = xbf + (size_t)BT_ * D_ / 2;  // f16 qkv / f16 h
    float* abf  = r1f + (size_t)BT_ * FF_ / 2; // f16 attn out
    float* r2   = abf + (size_t)BT_ * D_ / 2;  // partials (early) / f16 g (late)
    float* wtf  = r2  + (size_t)BT_ * D_;      // f16 weights
    float* sl   = wtf + 7077888;
    float* el   = sl  + BT_;
    float* dpar = el  + BT_;                   // DKS * D_ disc partials

    _Float16* xb    = (_Float16*)xbf;
    _Float16* qkv16 = (_Float16*)r1f;
    _Float16* h16   = (_Float16*)r1f;
    _Float16* ab    = (_Float16*)abf;
    float* pm   = r2;
    float* pl   = r2 + NEDGE * NSPLIT * 16;
    float* pacc = pl + NEDGE * NSPLIT * 16;
    _Float16* g16 = (_Float16*)r2;   // aliased; partials dead once proj runs

    _Float16* Wt    = (_Float16*)wtf;
    _Float16* WqkvT = Wt;
    _Float16* WoT   = WqkvT + (size_t)2 * 2304 * 768;
    _Float16* Wff1T = WoT   + (size_t)2 * 768 * 768;
    _Float16* Wff2T = Wff1T + (size_t)2 * 3072 * 768;

    for (int l = 0; l < 2; ++l) {
        wconvert_kernel<<<dim3(2304/32, 768/32), 256, 0, stream>>>(
            Wqkv + (size_t)l * 768 * 2304, WqkvT + (size_t)l * 2304 * 768, 768, 2304);
        wconvert_kernel<<<dim3(768/32, 768/32), 256, 0, stream>>>(
            Wo + (size_t)l * 768 * 768, WoT + (size_t)l * 768 * 768, 768, 768);
        wconvert_kernel<<<dim3(3072/32, 768/32), 256, 0, stream>>>(
            Wff1 + (size_t)l * 768 * 3072, Wff1T + (size_t)l * 3072 * 768, 768, 3072);
        wconvert_kernel<<<dim3(768/32, 3072/32), 256, 0, stream>>>(
            Wff2 + (size_t)l * 3072 * 768, Wff2T + (size_t)l * 768 * 3072, 3072, 768);
    }

    embed_kernel<<<BT_, 256, 0, stream>>>(ids, emb, x, xb);

    for (int l = 0; l < 2; ++l) {
        gemm_f16<0,1><<<dim3(2304/128, BT_/128), 256, 0, stream>>>(
            xb, WqkvT + (size_t)l * 2304 * 768, bqkv + (size_t)l * 3 * D_,
            qkv16, BT_, 3 * D_, D_);
        attn_sparse<<<B_ * H_ * NB_, 256, 0, stream>>>(qkv16, kbi, ab);
        attn_edge<<<NEDGE * NSPLIT, 256, 0, stream>>>(qkv16, pm, pl, pacc);
        attn_edge_combine<<<NEDGE, 256, 0, stream>>>(pm, pl, pacc, ab);
        gemm_f16<0,1><<<dim3(768/128, BT_/128), 256, 0, stream>>>(
            ab, WoT + (size_t)l * 768 * 768, bo + (size_t)l * D_,
            g16, BT_, D_, D_);
        add_ln_kernel<<<BT_, 256, 0, stream>>>(x, g16, ln1g + (size_t)l * D_, ln1b + (size_t)l * D_, xb);
        gemm_f16<1,1><<<dim3(3072/128, BT_/128), 256, 0, stream>>>(
            xb, Wff1T + (size_t)l * 3072 * 768, bff1 + (size_t)l * FF_,
            h16, BT_, FF_, D_);
        gemm_f16<0,1><<<dim3(768/128, BT_/128), 256, 0, stream>>>(
            h16, Wff2T + (size_t)l * 768 * 3072, bff2 + (size_t)l * D_,
            g16, BT_, D_, FF_);
        add_ln_kernel<<<BT_, 256, 0, stream>>>(x, g16, ln2g + (size_t)l * D_, ln2b + (size_t)l * D_, xb);
    }

    head_logits<<<BT_, 64, 0, stream>>>(x, sw, ew, sl, el);
    softmax_rows<<<4, 256, 0, stream>>>(sl, el, outp);
    disc_pool_partial<<<dim3(3, DKS), 256, 0, stream>>>(x, Wp, dpar);
    disc_finish<<<1, 256, 0, stream>>>(dpar, bp, d1W, d1b, d2W, d2b, outp + 2 * BT_);
}